// Round 13
// baseline (272.102 us; speedup 1.0000x reference)
//
#include <hip/hip_runtime.h>

typedef _Float16 half8 __attribute__((ext_vector_type(8)));
typedef float f32x4 __attribute__((ext_vector_type(4)));

#define TN    1000
#define TPAD  1024
#define NW    12          // u32 words per timestep (384 bits)
#define SPKW  392         // K2 LDS spike row stride (f16), 784B rows, 16B aligned
#define C2W   48          // c2 row stride (floats)

// ws layout:
//   wf16    @ 0         : 48*384 f16 = 36864 B   (padded fc_w, o>=35 zeroed)
//   spkbits @ 36864     : 256*1024*12 u32 = 12582912 B  (bit-packed spikes)
//   c2g     @ 12619776  : 256*1024*48 f32 = 50331648 B
// total 62951424 B (~63 MB)
#define WS_WF16   0
#define WS_SPK    36864
#define WS_C2     12619776

// ---------------- K0: cast fc_w to padded f16 once per call ----------------
__global__ void k0_wcast(const float* __restrict__ fc_w, _Float16* __restrict__ wf16)
{
    int i = threadIdx.x + blockIdx.x * 256;
    if (i < 48 * 384) {
        int o = i / 384, k = i % 384;
        wf16[i] = (o < 35) ? (_Float16)fc_w[o * 384 + k] : (_Float16)0.f;
    }
}

// ---------------- K1: conv + LIF1 -> bit-packed spikes (NO barriers) ----------------
// 256 blocks x 384 thr; lane = one neuron (c=tid/24, p=tid%24); serial over t
// with 8-step register ping-pong prefetch from global (rows 120B, L1-shared by
// 16 channels). Spikes exported via __ballot -> one u64 store per wave per step.
// Parity-shifted 8-tap weights keep float2 loads 8B-aligned (pe+30s always even).
__global__ __launch_bounds__(384, 1) void k1_conv_lif1(
    const float* __restrict__ x, const float* __restrict__ conv_w,
    const float* __restrict__ conv_b, unsigned long long* __restrict__ spk64)
{
    const int tid = threadIdx.x, b = blockIdx.x;
    const int wid = tid >> 6, lane = tid & 63;
    const int c = tid / 24, p = tid % 24;
    const int par = p & 1, pe = p - par;

    float wk8[8];
#pragma unroll
    for (int j = 0; j < 8; ++j) {
        int k = j - par;
        wk8[j] = (k >= 0 && k < 7) ? conv_w[c * 7 + k] : 0.f;
    }
    const float cb = conv_b[c];

    const float* xb = x + (size_t)b * (TN * 30) + pe;
    unsigned long long* sb = spk64 + (size_t)b * (TPAD * (NW / 2)) + wid;

    float m1 = 0.f, sp = 0.f;
    float2 XA[8][4], XB[8][4];

#define K1LOAD(X, CH)                                                         \
    { _Pragma("unroll")                                                       \
      for (int s = 0; s < 8; ++s) {                                           \
          const float2* p2 = (const float2*)(xb + ((CH) * 8 + s) * 30);       \
          X[s][0] = p2[0]; X[s][1] = p2[1]; X[s][2] = p2[2]; X[s][3] = p2[3]; \
      } }

#define K1COMP(X, CH)                                                         \
    { _Pragma("unroll")                                                       \
      for (int s = 0; s < 8; ++s) {                                           \
          float c1 = cb;                                                      \
          c1 = fmaf(wk8[0], X[s][0].x, c1);  c1 = fmaf(wk8[1], X[s][0].y, c1);\
          c1 = fmaf(wk8[2], X[s][1].x, c1);  c1 = fmaf(wk8[3], X[s][1].y, c1);\
          c1 = fmaf(wk8[4], X[s][2].x, c1);  c1 = fmaf(wk8[5], X[s][2].y, c1);\
          c1 = fmaf(wk8[6], X[s][3].x, c1);  c1 = fmaf(wk8[7], X[s][3].y, c1);\
          m1 = fmaf(0.9f, m1, c1 - sp);                                       \
          sp = (m1 > 1.0f) ? 1.0f : 0.0f;                                     \
          unsigned long long bal = __ballot(m1 > 1.0f);                       \
          if (lane == 0) sb[(size_t)((CH) * 8 + s) * (NW / 2)] = bal;         \
      } }

    K1LOAD(XA, 0)
#pragma unroll 1
    for (int ch = 0; ch < 124; ch += 2) {
        K1LOAD(XB, ch + 1)
        K1COMP(XA, ch)
        K1LOAD(XA, ch + 2)      // ch+2 <= 124 always
        K1COMP(XB, ch + 1)
    }
    K1COMP(XA, 124)
#undef K1LOAD
#undef K1COMP
}

// ---------------- K2: t-parallel FC GEMM (4096 independent blocks) ----------------
// block = (b, 64-timestep tile); 384 thr / 6 waves; unpack bits -> f16 LDS,
// ONE barrier, then wave (m=wid>>1, half=wid&1) does 2 x 16-col MFMA chains.
__global__ __launch_bounds__(384, 4) void k2_gemm(
    const unsigned* __restrict__ spkbits, const _Float16* __restrict__ wf16,
    float* __restrict__ c2g)
{
    __shared__ _Float16 spkL[64][SPKW];   // 50176 B

    const int tid = threadIdx.x;
    const int b = blockIdx.x >> 4, tile = blockIdx.x & 15;
    const int t0 = tile * 64;
    const int wid = tid >> 6, lane = tid & 63;
    const int nL = lane & 15, q = lane >> 4;
    const int m = wid >> 1, tb2 = wid & 1;

    // A fragments from pre-cast f16 weights (12 x 16B global loads, L2-hot)
    half8 A[12];
    {
        const _Float16* wp_ = wf16 + (m * 16 + nL) * 384 + q * 8;
#pragma unroll
        for (int kt = 0; kt < 12; ++kt)
            A[kt] = *(const half8*)(wp_ + kt * 32);
    }

    // unpack: thread (wp=tid>>6, tl=tid&63) expands 64 bits (2 words) for row tl
    {
        const int wp = tid >> 6, tl = tid & 63;
        const unsigned* src = spkbits + ((size_t)b * TPAD + (t0 + tl)) * NW + 2 * wp;
        unsigned w0 = src[0], w1 = src[1];
        unsigned* dst = (unsigned*)&spkL[tl][64 * wp];
#pragma unroll
        for (int j = 0; j < 16; ++j)
            dst[j] = (((w0 >> (2 * j)) & 1u) ? 0x3C00u : 0u) |
                     (((w0 >> (2 * j + 1)) & 1u) ? 0x3C000000u : 0u);
#pragma unroll
        for (int j = 0; j < 16; ++j)
            dst[16 + j] = (((w1 >> (2 * j)) & 1u) ? 0x3C00u : 0u) |
                          (((w1 >> (2 * j + 1)) & 1u) ? 0x3C000000u : 0u);
    }
    __syncthreads();

    float* cd = c2g + ((size_t)b * TPAD + t0 + tb2 * 32) * C2W;
#pragma unroll
    for (int nt = 0; nt < 2; ++nt) {
        const _Float16* sbt = &spkL[tb2 * 32 + nt * 16 + nL][0];
        half8 B[12];
#pragma unroll
        for (int kt = 0; kt < 12; ++kt)
            B[kt] = *(const half8*)(sbt + kt * 32 + q * 8);
        f32x4 acc = {0.f, 0.f, 0.f, 0.f};
#pragma unroll
        for (int kt = 0; kt < 12; ++kt)
            acc = __builtin_amdgcn_mfma_f32_16x16x32_f16(A[kt], B[kt], acc, 0, 0, 0);
        // C/D: col = lane&15 (t_local), row = q*4+i (o_local)
        *(f32x4*)(cd + (nt * 16 + nL) * C2W + m * 16 + q * 4) = acc;
    }
}

// ---------------- K3: LIF2 scan + mean (256 blocks x 1 wave) ----------------
__global__ __launch_bounds__(64, 1) void k3_scan(
    const float* __restrict__ c2g, const float* __restrict__ fc_b,
    float* __restrict__ out)
{
    const int lane = threadIdx.x, b = blockIdx.x;
    const bool act = lane < 35;
    const float fcb = act ? fc_b[lane] : 0.f;
    const float* cs = c2g + (size_t)b * TPAD * C2W + (act ? lane : 0);

    float mem2 = 0.f, accO = 0.f;
    float VA[8], VB[8];
#pragma unroll
    for (int j = 0; j < 8; ++j) VA[j] = cs[j * C2W];

#define K3COMP(V)                                                             \
    { _Pragma("unroll")                                                       \
      for (int j = 0; j < 8; ++j) {                                           \
          float r2 = (mem2 > 1.0f) ? 1.0f : 0.0f;                             \
          mem2 = 0.9f * mem2 + (V[j] + fcb) - r2;                             \
          accO += mem2;                                                       \
      } }

#pragma unroll 1
    for (int ch = 0; ch < 124; ch += 2) {
#pragma unroll
        for (int j = 0; j < 8; ++j) VB[j] = cs[((ch + 1) * 8 + j) * C2W];
        K3COMP(VA)
#pragma unroll
        for (int j = 0; j < 8; ++j) VA[j] = cs[((ch + 2) * 8 + j) * C2W];
        K3COMP(VB)
    }
    K3COMP(VA)   // chunk 124
#undef K3COMP

    if (act) out[b * 35 + lane] = accO * (1.0f / (float)TN);
}

extern "C" void kernel_launch(void* const* d_in, const int* in_sizes, int n_in,
                              void* d_out, int out_size, void* d_ws, size_t ws_size,
                              hipStream_t stream) {
    const float* x      = (const float*)d_in[0];
    const float* conv_w = (const float*)d_in[1];
    const float* conv_b = (const float*)d_in[2];
    const float* fc_w   = (const float*)d_in[3];
    const float* fc_b   = (const float*)d_in[4];
    float* out          = (float*)d_out;

    char* ws = (char*)d_ws;
    _Float16*           wf16    = (_Float16*)(ws + WS_WF16);
    unsigned*           spkbits = (unsigned*)(ws + WS_SPK);
    unsigned long long* spk64   = (unsigned long long*)(ws + WS_SPK);
    float*              c2g     = (float*)(ws + WS_C2);

    k0_wcast    <<<72,   256, 0, stream>>>(fc_w, wf16);
    k1_conv_lif1<<<256,  384, 0, stream>>>(x, conv_w, conv_b, spk64);
    k2_gemm     <<<4096, 384, 0, stream>>>(spkbits, wf16, c2g);
    k3_scan     <<<256,  64,  0, stream>>>(c2g, fc_b, out);
}